// Round 5
// baseline (680.192 us; speedup 1.0000x reference)
//
#include <hip/hip_runtime.h>

#define DIM 1536
#define IMG 1024
#define TXT 256
#define SEQ 1280
#define NH 24
#define HD 64
#define SD ((size_t)SEQ * DIM)
#define IDSZ ((size_t)IMG * DIM)
#define WSZ ((size_t)DIM * DIM)

typedef __attribute__((ext_vector_type(8))) short short8;
typedef __attribute__((ext_vector_type(4))) float f32x4;

__device__ __forceinline__ float bf2f(ushort u) {
    union { unsigned int i; float f; } v; v.i = ((unsigned int)u) << 16; return v.f;
}
__device__ __forceinline__ ushort f2bf(float f) {
    union { unsigned int i; float f; } v; v.f = f;
    unsigned int u = v.i;
    u += 0x7fffu + ((u >> 16) & 1u);
    return (ushort)(u >> 16);
}
// Packed f32x2 -> bf16x2 (low = a, high = b). RNE on gfx950; any rounding
// drift is absorbed by the residual-lo plane.
__device__ __forceinline__ unsigned int cvtpk(float a, float b) {
    unsigned int r;
    asm("v_cvt_pk_bf16_f32 %0, %1, %2" : "=v"(r) : "v"(a), "v"(b));
    return r;
}

// ---------------------------------------------------------------------------
// Input-dtype detector (flag=1 -> fp32 underneath, flag=0 -> bf16).
// ---------------------------------------------------------------------------
__global__ __launch_bounds__(256) void detect_dtype(const void* __restrict__ p,
                                                    int* __restrict__ flag)
{
    __shared__ int cnt;
    if (threadIdx.x == 0) cnt = 0;
    __syncthreads();
    const ushort* u = (const ushort*)p;
    int local = 0;
    for (int i = threadIdx.x; i < 2048; i += 256) {
        ushort v = u[2 * i];
        int e = (v >> 7) & 0xFF;
        if (e >= 0xC0) local++;
    }
    atomicAdd(&cnt, local);
    __syncthreads();
    if (threadIdx.x == 0) flag[0] = (cnt > 16) ? 1 : 0;
}

// ---------------------------------------------------------------------------
// One-time bf16 conversion: 16 weights (12 qkv + 4 out) + 4 X inputs.
// ---------------------------------------------------------------------------
struct CvtP {
    const void* src[20];
    ushort* dst[20];
    int n8[20];
};

__global__ __launch_bounds__(256) void convert_bf16(CvtP p, const int* __restrict__ dflag)
{
    const int a = blockIdx.y;
    const int i = blockIdx.x * 256 + threadIdx.x;
    if (i >= p.n8[a]) return;
    const size_t off = (size_t)i * 8;
    uint4 o;
    if (dflag[0]) {
        const float* s = (const float*)p.src[a] + off;
        const float4 f0 = *(const float4*)s;
        const float4 f1 = *(const float4*)(s + 4);
        ushort t[8];
        t[0] = f2bf(f0.x); t[1] = f2bf(f0.y); t[2] = f2bf(f0.z); t[3] = f2bf(f0.w);
        t[4] = f2bf(f1.x); t[5] = f2bf(f1.y); t[6] = f2bf(f1.z); t[7] = f2bf(f1.w);
        o = *(uint4*)t;
    } else {
        o = *(const uint4*)((const ushort*)p.src[a] + off);
    }
    *(uint4*)(p.dst[a] + off) = o;
}

#define LSTR 40

// ===========================================================================
// Merged QKV GEMM over pre-converted bf16 X and W. grid (36, 20).
// B plane: 128 n-rows folded into 64 LDS rows of 64 ushorts, granule XOR
// gx = ((half<<2)+g) ^ (R&7) ^ (R>>3).
// ===========================================================================
struct QKV3P {
    const ushort* Xb;    // [2][SEQ][DIM] bf16
    const ushort* Wb;    // [12][DIM][DIM] bf16, idx = str*6 + wsel + istxt*3
    const void* B[12];
    float* Y[6];
    ushort* Yh[6];
    ushort* Yl[6];
};

__global__ __launch_bounds__(256) void gemm_qkv_v4(QKV3P p, const int* __restrict__ dflag)
{
    __shared__ __align__(16) ushort As[2][128 * LSTR];
    __shared__ __align__(16) ushort Bs[2][64 * 64];
    const int dt = dflag[0];
    const int bx = blockIdx.x;
    const int wsel = bx / 12;
    const int n0 = (bx - wsel * 12) * 128;
    const int ys = blockIdx.y;
    const int str = (ys >= 10) ? 1 : 0;
    const int m0g = (ys - str * 10) * 128;
    const bool istxt = (m0g >= IMG);
    const int widx = str * 6 + wsel + (istxt ? 3 : 0);
    const ushort* X  = p.Xb + (size_t)str * SD;
    const ushort* Wp = p.Wb + (size_t)widx * WSZ;
    const void* Bp = p.B[widx];
    const int yidx = str * 3 + wsel;
    float*  Y  = p.Y[yidx];
    ushort* yh = p.Yh[yidx];
    ushort* yl = p.Yl[yidx];

    const int t = threadIdx.x;
    const int wave = t >> 6, lane = t & 63;
    const int quad = lane >> 4, l16 = lane & 15;
    const int wm = (wave >> 1) * 64, wn = (wave & 1) * 64;

    const int arow = t >> 1, apair = t & 1;
    const int bn8 = (t & 15) << 3, bkk = (t >> 4) << 1;
    const int aps = apair ^ ((arow >> 3) & 1);
    const int adst = arow * LSTR + aps * 16;
    const int bkg = bkk >> 3, bo = bkk & 7;

    f32x4 acc[4][4];
#pragma unroll
    for (int i = 0; i < 4; ++i)
#pragma unroll
        for (int j = 0; j < 4; ++j) acc[i][j] = (f32x4)(0.0f);

    uint4 rau[2];
    uint4 rbu[2];

    auto loadA = [&](int k0) {
        const ushort* xp = X + (size_t)(m0g + arow) * DIM + k0 + apair * 16;
        rau[0] = *(const uint4*)xp;
        rau[1] = *(const uint4*)(xp + 8);
    };
    auto loadB = [&](int k0) {
        const ushort* wp0 = Wp + (size_t)(k0 + bkk) * DIM + n0 + bn8;
        rbu[0] = *(const uint4*)wp0;
        rbu[1] = *(const uint4*)(wp0 + DIM);
    };
    auto storeA = [&](int buf) {
        *(uint4*)&As[buf][adst]     = rau[0];
        *(uint4*)&As[buf][adst + 8] = rau[1];
    };
    auto storeB = [&](int buf) {
        ushort t0[8], t1[8];
        *(uint4*)t0 = rbu[0];
        *(uint4*)t1 = rbu[1];
#pragma unroll
        for (int j = 0; j < 8; ++j) {
            const int rr = bn8 + j;
            const int R = rr & 63, half = rr >> 6;
            const int gx = (((half << 2) + bkg) ^ (R & 7) ^ (R >> 3)) & 7;
            *(unsigned int*)&Bs[buf][R * 64 + gx * 8 + bo] =
                (unsigned int)t0[j] | ((unsigned int)t1[j] << 16);
        }
    };

    loadA(0); loadB(0);
    storeA(0); storeB(0);
    __syncthreads();

    for (int k = 0; k < DIM / 32; ++k) {
        const int cur = k & 1;
        const bool hn = (k + 1) < DIM / 32;
        if (hn) { loadA((k + 1) * 32); loadB((k + 1) * 32); }

        short8 b[4];
#pragma unroll
        for (int j = 0; j < 4; ++j) {
            const int rrn = wn + j * 16 + l16;
            const int R = rrn & 63, half = rrn >> 6;
            const int gx = (((half << 2) + quad) ^ (R & 7) ^ (R >> 3)) & 7;
            b[j] = *(const short8*)&Bs[cur][R * 64 + gx * 8];
        }
#pragma unroll
        for (int i = 0; i < 4; ++i) {
            const int rr = wm + i * 16 + l16;
            const int ps = (quad >> 1) ^ ((rr >> 3) & 1);
            const int col = ps * 16 + (quad & 1) * 8;
            short8 a = *(const short8*)&As[cur][rr * LSTR + col];
#pragma unroll
            for (int j = 0; j < 4; ++j)
                acc[i][j] = __builtin_amdgcn_mfma_f32_16x16x32_bf16(a, b[j], acc[i][j], 0, 0, 0);
        }
        if (hn) { storeA(cur ^ 1); storeB(cur ^ 1); }
        __syncthreads();
    }

#pragma unroll
    for (int j = 0; j < 4; ++j) {
        const int col = n0 + wn + j * 16 + l16;
        const float bv = dt ? ((const float*)Bp)[col] : bf2f(((const ushort*)Bp)[col]);
#pragma unroll
        for (int i = 0; i < 4; ++i)
#pragma unroll
            for (int r = 0; r < 4; ++r) {
                const int row = m0g + wm + i * 16 + quad * 4 + r;
                const size_t o = (size_t)row * DIM + col;
                const float val = acc[i][j][r] + bv;
                if (Y) Y[o] = val;
                if (yh) {
                    const ushort hv = f2bf(val);
                    yh[o] = hv;
                    yl[o] = f2bf(val - bf2f(hv));
                }
            }
    }
}

// ===========================================================================
// Output projections from pre-split bf16 A planes (Xh/Xl, 2560 rows) and
// pre-converted bf16 weights. grid (12, 40), 64-row m-tiles.
// ===========================================================================
struct OutP {
    const ushort* Xh; const ushort* Xl;
    const ushort* Wb;    // 4 * WSZ bf16
    const void* B[4];
    void* out;
};

__global__ __launch_bounds__(256) void gemm_out_v4(OutP p, const int* __restrict__ dflag)
{
    __shared__ __align__(16) ushort Ah[2][64 * LSTR];
    __shared__ __align__(16) ushort Al[2][64 * LSTR];
    __shared__ __align__(16) ushort Bs[2][64 * 64];
    const int dt = dflag[0];
    const int n0 = blockIdx.x * 128;
    const int mt = blockIdx.y;
    const int seg = (mt < 16) ? 0 : (mt < 20) ? 1 : (mt < 36) ? 2 : 3;
    const ushort* Wp = p.Wb + (size_t)seg * WSZ;
    const void* Bp = p.B[seg];
    const int m0 = mt * 64;

    const int t = threadIdx.x;
    const int wave = t >> 6, lane = t & 63;
    const int quad = lane >> 4, l16 = lane & 15;
    const int wm = (wave >> 1) * 32, wn = (wave & 1) * 64;

    const int arow = t >> 2, ag = t & 3;
    const int apg = ag >> 1, asub = ag & 1;
    const int aps = apg ^ ((arow >> 3) & 1);
    const int adst = arow * LSTR + aps * 16 + asub * 8;
    const int bn8 = (t & 15) << 3, bkk = (t >> 4) << 1;
    const int bkg = bkk >> 3, bo = bkk & 7;

    f32x4 acc[2][4];
#pragma unroll
    for (int i = 0; i < 2; ++i)
#pragma unroll
        for (int j = 0; j < 4; ++j) acc[i][j] = (f32x4)(0.0f);

    uint4 rah, ral;
    uint4 rbu[2];

    auto loadA = [&](int k0) {
        const size_t off = (size_t)(m0 + arow) * DIM + k0 + ag * 8;
        rah = *(const uint4*)(p.Xh + off);
        ral = *(const uint4*)(p.Xl + off);
    };
    auto loadB = [&](int k0) {
        const ushort* wp0 = Wp + (size_t)(k0 + bkk) * DIM + n0 + bn8;
        rbu[0] = *(const uint4*)wp0;
        rbu[1] = *(const uint4*)(wp0 + DIM);
    };
    auto storeA = [&](int buf) {
        *(uint4*)&Ah[buf][adst] = rah;
        *(uint4*)&Al[buf][adst] = ral;
    };
    auto storeB = [&](int buf) {
        ushort t0[8], t1[8];
        *(uint4*)t0 = rbu[0];
        *(uint4*)t1 = rbu[1];
#pragma unroll
        for (int j = 0; j < 8; ++j) {
            const int rr = bn8 + j;
            const int R = rr & 63, half = rr >> 6;
            const int gx = (((half << 2) + bkg) ^ (R & 7) ^ (R >> 3)) & 7;
            *(unsigned int*)&Bs[buf][R * 64 + gx * 8 + bo] =
                (unsigned int)t0[j] | ((unsigned int)t1[j] << 16);
        }
    };

    loadA(0); loadB(0);
    storeA(0); storeB(0);
    __syncthreads();

    for (int k = 0; k < DIM / 32; ++k) {
        const int cur = k & 1;
        const bool hn = (k + 1) < DIM / 32;
        if (hn) { loadA((k + 1) * 32); loadB((k + 1) * 32); }

        short8 b[4];
#pragma unroll
        for (int j = 0; j < 4; ++j) {
            const int rrn = wn + j * 16 + l16;
            const int R = rrn & 63, half = rrn >> 6;
            const int gx = (((half << 2) + quad) ^ (R & 7) ^ (R >> 3)) & 7;
            b[j] = *(const short8*)&Bs[cur][R * 64 + gx * 8];
        }
#pragma unroll
        for (int i = 0; i < 2; ++i) {
            const int rr = wm + i * 16 + l16;
            const int ps = (quad >> 1) ^ ((rr >> 3) & 1);
            const int col = ps * 16 + (quad & 1) * 8;
            short8 ah = *(const short8*)&Ah[cur][rr * LSTR + col];
            short8 al = *(const short8*)&Al[cur][rr * LSTR + col];
#pragma unroll
            for (int j = 0; j < 4; ++j) {
                acc[i][j] = __builtin_amdgcn_mfma_f32_16x16x32_bf16(ah, b[j], acc[i][j], 0, 0, 0);
                acc[i][j] = __builtin_amdgcn_mfma_f32_16x16x32_bf16(al, b[j], acc[i][j], 0, 0, 0);
            }
        }
        if (hn) { storeA(cur ^ 1); storeB(cur ^ 1); }
        __syncthreads();
    }

#pragma unroll
    for (int j = 0; j < 4; ++j) {
        const int col = n0 + wn + j * 16 + l16;
        const float bv = dt ? ((const float*)Bp)[col] : bf2f(((const ushort*)Bp)[col]);
#pragma unroll
        for (int i = 0; i < 2; ++i)
#pragma unroll
            for (int r = 0; r < 4; ++r) {
                const int grow = m0 + wm + i * 16 + quad * 4 + r;
                const size_t o = (size_t)grow * DIM + col;
                const float val = acc[i][j][r] + bv;
                if (dt) ((float*)p.out)[o] = val;
                else    ((ushort*)p.out)[o] = f2bf(val);
            }
    }
}

// ---------------------------------------------------------------------------
// Fused prep: vtrans (both streams) + all three RoPE jobs in one launch.
// ---------------------------------------------------------------------------
__device__ __forceinline__ void pe_load(const void* pe, int dt, size_t off,
                                        float& c00, float& c01, float& c10, float& c11)
{
    if (dt) {
        float4 pv = *(const float4*)((const float*)pe + off);
        c00 = pv.x; c01 = pv.y; c10 = pv.z; c11 = pv.w;
    } else {
        const ushort* pp = (const ushort*)pe + off;
        c00 = bf2f(pp[0]); c01 = bf2f(pp[1]); c10 = bf2f(pp[2]); c11 = bf2f(pp[3]);
    }
}

struct PrepP {
    const float* v1; const float* vC;
    ushort *vthA, *vtlA, *vthC, *vtlC;
    float* q1;
    const float* k1; ushort *khC, *kloC;
    const void* i2q; float* qx;
    const void* pe;
};

#define VT_BLKS 960
#define RN0 (SEQ * 768)
#define RN1 (SEQ * 768)
#define RN2 (IMG * 768)

__global__ __launch_bounds__(256) void prep_fused(PrepP p, const int* __restrict__ dflag)
{
    __shared__ unsigned int tile[64 * 65];
    const int dt = dflag[0];
    const int bx = blockIdx.x;
    const int t = threadIdx.x;

    if (bx < VT_BLKS) {
        const int z = bx / 480, rem = bx - z * 480;
        const int s0 = (rem % 20) * 64, h = rem / 20;
        const float* V = z ? p.vC : p.v1;
        ushort* Vth = z ? p.vthC : p.vthA;
        ushort* Vtl = z ? p.vtlC : p.vtlA;
#pragma unroll
        for (int it = 0; it < 16; ++it) {
            const int sl = (t >> 6) + (it << 2);
            const int d = t & 63;
            const float v = V[(size_t)(s0 + sl) * DIM + h * HD + d];
            const ushort hv = f2bf(v);
            const ushort lv = f2bf(v - bf2f(hv));
            tile[d * 65 + sl] = (unsigned int)hv | ((unsigned int)lv << 16);
        }
        __syncthreads();
        const int d = t >> 2, cc = (t & 3) << 4;
        ushort th[16], tl[16];
#pragma unroll
        for (int j = 0; j < 16; ++j) {
            const unsigned int w = tile[d * 65 + cc + j];
            th[j] = (ushort)w;
            tl[j] = (ushort)(w >> 16);
        }
        const size_t off = (size_t)(h * HD + d) * SEQ + s0 + cc;
        *(uint4*)(Vth + off)     = *(uint4*)&th[0];
        *(uint4*)(Vth + off + 8) = *(uint4*)&th[8];
        *(uint4*)(Vtl + off)     = *(uint4*)&tl[0];
        *(uint4*)(Vtl + off + 8) = *(uint4*)&tl[8];
        return;
    }

    int idx = (bx - VT_BLKS) * 256 + t;
    if (idx < RN0) {
        int s = idx / 768, pp = idx - s * 768;
        int col = pp << 1, i = pp & 31;
        float* bp = p.q1 + (size_t)s * DIM + col;
        float x0 = bp[0], x1 = bp[1];
        float c00, c01, c10, c11;
        pe_load(p.pe, dt, (size_t)s * 128 + i * 4, c00, c01, c10, c11);
        bp[0] = c00 * x0 + c01 * x1;
        bp[1] = c10 * x0 + c11 * x1;
        return;
    }
    idx -= RN0;
    if (idx < RN1) {
        int s = idx / 768, pp = idx - s * 768;
        int col = pp << 1, i = pp & 31;
        float2 xv = *(const float2*)(p.k1 + (size_t)s * DIM + col);
        float c00, c01, c10, c11;
        pe_load(p.pe, dt, (size_t)s * 128 + i * 4, c00, c01, c10, c11);
        float y0 = c00 * xv.x + c01 * xv.y;
        float y1 = c10 * xv.x + c11 * xv.y;
        ushort h0 = f2bf(y0), h1 = f2bf(y1);
        ushort l0 = f2bf(y0 - bf2f(h0)), l1 = f2bf(y1 - bf2f(h1));
        *(unsigned int*)(p.khC  + (size_t)s * DIM + col) = (unsigned int)h0 | ((unsigned int)h1 << 16);
        *(unsigned int*)(p.kloC + (size_t)s * DIM + col) = (unsigned int)l0 | ((unsigned int)l1 << 16);
        return;
    }
    idx -= RN1;
    if (idx < RN2) {
        int s = idx / 768, pp = idx - s * 768;
        int col = pp << 1, i = pp & 31;
        float x0, x1;
        if (dt) {
            float2 xv = *(const float2*)((const float*)p.i2q + (size_t)s * DIM + col);
            x0 = xv.x; x1 = xv.y;
        } else {
            const ushort* sp = (const ushort*)p.i2q + (size_t)s * DIM + col;
            x0 = bf2f(sp[0]); x1 = bf2f(sp[1]);
        }
        float c00, c01, c10, c11;
        pe_load(p.pe, dt, (size_t)s * 128 + i * 4, c00, c01, c10, c11);
        float* dp = p.qx + (size_t)s * DIM + col;
        dp[0] = c00 * x0 + c01 * x1;
        dp[1] = c10 * x0 + c11 * x1;
    }
}

// ---------------------------------------------------------------------------
// MFMA flash attention, all three attentions in one launch. grid (56, NH, 2).
// v5: launch_bounds(256,3), precomputed LDS offsets, scale folded into Q,
// cvt_pk P-store, async staging (loads issued before compute, writes after).
// ---------------------------------------------------------------------------
__device__ __forceinline__ int swz(int row, int col) {
    return row * 64 + ((((col >> 3) ^ row) & 7) << 3) + (col & 7);
}

struct AttnAllP {
    const float* Qf[3];
    const ushort* Kh[3]; const ushort* Kl[3];
    const ushort* Vth[3]; const ushort* Vtl[3];
    float* Op0[3]; float* Op1[3];
    float2* Ml[3];
    int mlq[3];
};

#define NKT 10

__global__ __launch_bounds__(256, 3) void attn_all(AttnAllP p)
{
    __shared__ ushort Qh_[4096], Ql_[4096];
    __shared__ ushort Kh_[4096], Kl_[4096];
    __shared__ ushort Vh_[4096], Vl_[4096];

    const int bx = blockIdx.x;
    const int seg = (bx < 20) ? 0 : (bx < 40) ? 1 : 2;
    const int q0 = (bx - ((seg == 0) ? 0 : (seg == 1) ? 20 : 40)) * 64;
    const int h = blockIdx.y;
    const int z = blockIdx.z;
    const int t = threadIdx.x;
    const int wave = t >> 6, lane = t & 63;
    const int quad = lane >> 4, l16 = lane & 15;
    const int wq0 = wave * 16;

    const float* Qf = p.Qf[seg];
    const ushort* Kh = p.Kh[seg]; const ushort* Kl = p.Kl[seg];
    const ushort* Vth = p.Vth[seg]; const ushort* Vtl = p.Vtl[seg];

    const int srow = t >> 2, c0 = (t & 3) << 4;
    const int g0 = c0 >> 3;
    const int p0 = ((g0 ^ (srow & 7)) & 7) << 3;
    const int p1 = (((g0 + 1) ^ (srow & 7)) & 7) << 3;

    // ---- loop-invariant LDS offsets (registers) ----
    int offF[2];        // Q/P A-fragment (row wq0+l16)
    int offB2[4][2];    // K/V B-fragment (row j*16+l16)
#pragma unroll
    for (int c = 0; c < 2; ++c) {
        offF[c] = swz(wq0 + l16, c * 32 + quad * 8);
#pragma unroll
        for (int j = 0; j < 4; ++j)
            offB2[j][c] = swz(j * 16 + l16, c * 32 + quad * 8);
    }
    const int prow = wq0 + quad * 4;
    int pidx[4][4];     // P-store (row prow+r, col j*16+l16)
#pragma unroll
    for (int j = 0; j < 4; ++j)
#pragma unroll
        for (int r = 0; r < 4; ++r)
            pidx[j][r] = swz(prow + r, j * 16 + l16);

    // ---- Q staging, 0.125 softmax scale folded in (exact pow2) ----
    {
        const float* src = Qf + (size_t)(q0 + srow) * DIM + h * HD + c0;
        float x[16];
        *(float4*)&x[0]  = *(const float4*)(src);
        *(float4*)&x[4]  = *(const float4*)(src + 4);
        *(float4*)&x[8]  = *(const float4*)(src + 8);
        *(float4*)&x[12] = *(const float4*)(src + 12);
        ushort hi[16], lo[16];
#pragma unroll
        for (int i = 0; i < 16; ++i) {
            const float xs = x[i] * 0.125f;
            hi[i] = f2bf(xs);
            lo[i] = f2bf(xs - bf2f(hi[i]));
        }
        *(uint4*)&Qh_[srow * 64 + p0] = *(uint4*)&hi[0];
        *(uint4*)&Qh_[srow * 64 + p1] = *(uint4*)&hi[8];
        *(uint4*)&Ql_[srow * 64 + p0] = *(uint4*)&lo[0];
        *(uint4*)&Ql_[srow * 64 + p1] = *(uint4*)&lo[8];
    }
    // Within-wave store->read (wave stages its own 16 rows; no barrier).
    short8 qfh[2], qfl[2];
#pragma unroll
    for (int c = 0; c < 2; ++c) {
        qfh[c] = *(const short8*)&Qh_[offF[c]];
        qfl[c] = *(const short8*)&Ql_[offF[c]];
    }

    float m_[4], l_[4];
#pragma unroll
    for (int r = 0; r < 4; ++r) { m_[r] = -3e38f; l_[r] = 0.0f; }
    f32x4 Oacc[4];
#pragma unroll
    for (int j = 0; j < 4; ++j) Oacc[j] = (f32x4)(0.0f);

    const int kvbeg = z * (SEQ / 2);

    uint4 rk[4], rv[4];
    auto loadKV = [&](int kv0) {
        const size_t ko = (size_t)(kv0 + srow) * DIM + h * HD + c0;
        rk[0] = *(const uint4*)(Kh + ko);
        rk[1] = *(const uint4*)(Kh + ko + 8);
        rk[2] = *(const uint4*)(Kl + ko);
        rk[3] = *(const uint4*)(Kl + ko + 8);
        const size_t vo = (size_t)(h * HD + srow) * SEQ + kv0 + c0;
        rv[0] = *(const uint4*)(Vth + vo);
        rv[1] = *(const uint4*)(Vth + vo + 8);
        rv[2] = *(const uint4*)(Vtl + vo);
        rv[3] = *(const uint4*)(Vtl + vo + 8);
    };
    auto writeKV = [&]() {
        *(uint4*)&Kh_[srow * 64 + p0] = rk[0];
        *(uint4*)&Kh_[srow * 64 + p1] = rk[1];
        *(uint4*)&Kl_[srow * 64 + p0] = rk[2];
        *(uint4*)&Kl_[srow * 64 + p1] = rk[3];
        *(uint4*)&Vh_[srow * 64 + p0] = rv[0];
        *(uint4*)&Vh_[srow * 64 + p1] = rv[1];
        *(uint4*)&Vl_[srow * 64 + p0] = rv[2];
        *(uint4*)&Vl_[srow * 64 + p1] = rv[3];
    };

    loadKV(kvbeg);
    writeKV();
    __syncthreads();

    for (int kt = 0; kt < NKT; ++kt) {
        const bool hn = (kt + 1) < NKT;
        if (hn) loadKV(kvbeg + (kt + 1) * 64);   // async: hides under compute

        f32x4 S[4];
#pragma unroll
        for (int j = 0; j < 4; ++j) S[j] = (f32x4)(0.0f);
        __builtin_amdgcn_s_setprio(1);
#pragma unroll
        for (int c = 0; c < 2; ++c) {
#pragma unroll
            for (int j = 0; j < 4; ++j) {
                short8 bh = *(const short8*)&Kh_[offB2[j][c]];
                short8 bl = *(const short8*)&Kl_[offB2[j][c]];
                S[j] = __builtin_amdgcn_mfma_f32_16x16x32_bf16(qfh[c], bh, S[j], 0, 0, 0);
                S[j] = __builtin_amdgcn_mfma_f32_16x16x32_bf16(qfl[c], bh, S[j], 0, 0, 0);
                S[j] = __builtin_amdgcn_mfma_f32_16x16x32_bf16(qfh[c], bl, S[j], 0, 0, 0);
            }
        }
        __builtin_amdgcn_s_setprio(0);

        float alpha[4];
#pragma unroll
        for (int r = 0; r < 4; ++r) {
            float mx = fmaxf(fmaxf(S[0][r], S[1][r]), fmaxf(S[2][r], S[3][r]));
            mx = fmaxf(mx, __shfl_xor(mx, 1));
            mx = fmaxf(mx, __shfl_xor(mx, 2));
            mx = fmaxf(mx, __shfl_xor(mx, 4));
            mx = fmaxf(mx, __shfl_xor(mx, 8));
            float mn = fmaxf(m_[r], mx);
            alpha[r] = __expf(m_[r] - mn);
            m_[r] = mn;
            float rs = 0.0f;
#pragma unroll
            for (int j = 0; j < 4; ++j) {
                float pv = __expf(S[j][r] - mn);
                S[j][r] = pv;
                rs += pv;
            }
            rs += __shfl_xor(rs, 1);
            rs += __shfl_xor(rs, 2);
            rs += __shfl_xor(rs, 4);
            rs += __shfl_xor(rs, 8);
            l_[r] = l_[r] * alpha[r] + rs;
        }
#pragma unroll
        for (int j = 0; j < 4; ++j)
#pragma unroll
            for (int r = 0; r < 4; ++r) Oacc[j][r] *= alpha[r];

        // ---- P -> hi/lo planes via packed bf16 converts ----
#pragma unroll
        for (int j = 0; j < 4; ++j) {
            const unsigned int h01 = cvtpk(S[j][0], S[j][1]);
            const unsigned int h23 = cvtpk(S[j][2], S[j][3]);
            union { unsigned int u; float f; } b0, b1, b2, b3;
            b0.u = h01 << 16; b1.u = h01 & 0xffff0000u;
            b2.u = h23 << 16; b3.u = h23 & 0xffff0000u;
            const unsigned int l01 = cvtpk(S[j][0] - b0.f, S[j][1] - b1.f);
            const unsigned int l23 = cvtpk(S[j][2] - b2.f, S[j][3] - b3.f);
            Qh_[pidx[j][0]] = (ushort)h01;
            Qh_[pidx[j][1]] = (ushort)(h01 >> 16);
            Qh_[pidx[j][2]] = (ushort)h23;
            Qh_[pidx[j][3]] = (ushort)(h23 >> 16);
            Ql_[pidx[j][0]] = (ushort)l01;
            Ql_[pidx[j][1]] = (ushort)(l01 >> 16);
            Ql_[pidx[j][2]] = (ushort)l23;
            Ql_[pidx[j][3]] = (ushort)(l23 >> 16);
        }

        __builtin_amdgcn_s_setprio(1);
#pragma unroll
        for (int c = 0; c < 2; ++c) {
            short8 pah = *(const short8*)&Qh_[offF[c]];
            short8 pal = *(const short8*)&Ql_[offF[c]];
#pragma unroll
            for (int jn = 0; jn < 4; ++jn) {
                short8 vbh = *(const short8*)&Vh_[offB2[jn][c]];
                short8 vbl = *(const short8*)&Vl_[offB2[jn][c]];
                Oacc[jn] = __builtin_amdgcn_mfma_f32_16x16x32_bf16(pah, vbh, Oacc[jn], 0, 0, 0);
                Oacc[jn] = __builtin_amdgcn_mfma_f32_16x16x32_bf16(pal, vbh, Oacc[jn], 0, 0, 0);
                Oacc[jn] = __builtin_amdgcn_mfma_f32_16x16x32_bf16(pah, vbl, Oacc[jn], 0, 0, 0);
            }
        }
        __builtin_amdgcn_s_setprio(0);

        if (hn) {
            __syncthreads();       // all waves done reading K/V LDS
            writeKV();             // vmcnt-waited by compiler
            __syncthreads();       // next tile ready
        }
    }

    float* Opz = z ? p.Op1[seg] : p.Op0[seg];
    const int mlq = p.mlq[seg];
    float2* Ml = p.Ml[seg];
#pragma unroll
    for (int r = 0; r < 4; ++r) {
        const int rowq = q0 + wq0 + quad * 4 + r;
        if (l16 == 0)
            Ml[((size_t)z * NH + h) * mlq + rowq] = make_float2(m_[r], l_[r]);
#pragma unroll
        for (int jn = 0; jn < 4; ++jn)
            Opz[(size_t)rowq * DIM + h * HD + jn * 16 + l16] = Oacc[jn][r];
    }
}

// ---------------------------------------------------------------------------
// Unified merge: combines z-partials for A/C/X, folds cross residual into A,
// emits the out-proj A operand as bf16 hi/lo planes (2560 rows).
// ---------------------------------------------------------------------------
struct MergeP {
    const float *pA0, *pA1, *pC0, *pC1, *pX0, *pX1;
    const float2 *MlA, *MlC, *MlX;
    ushort *Xh, *Xl;
};

__device__ __forceinline__ float4 comb2(const float* O0, const float* O1,
                                        const float2* Ml, int mlq, int row, int c4)
{
    const int h = c4 >> 6;
    const float2 a = Ml[(size_t)h * mlq + row];
    const float2 b = Ml[(size_t)(NH + h) * mlq + row];
    const float ms = fmaxf(a.x, b.x);
    const float s0 = __expf(a.x - ms), s1 = __expf(b.x - ms);
    const float inv = 1.0f / (s0 * a.y + s1 * b.y);
    const float4 o0 = *(const float4*)&O0[(size_t)row * DIM + c4];
    const float4 o1 = *(const float4*)&O1[(size_t)row * DIM + c4];
    float4 r;
    r.x = (s0 * o0.x + s1 * o1.x) * inv;
    r.y = (s0 * o0.y + s1 * o1.y) * inv;
    r.z = (s0 * o0.z + s1 * o1.z) * inv;
    r.w = (s0 * o0.w + s1 * o1.w) * inv;
    return r;
}

__global__ __launch_bounds__(256) void merge_all(MergeP p)
{
    const int idx = blockIdx.x * 256 + threadIdx.x;
    if (idx >= 2560 * 384) return;
    const int row = idx / 384;
    const int c4 = (idx - row * 384) << 2;
    float4 r;
    if (row < SEQ) {
        r = comb2(p.pA0, p.pA1, p.MlA, SEQ, row, c4);
        if (row < IMG) {
            const float4 x = comb2(p.pX0, p.pX1, p.MlX, IMG, row, c4);
            r.x += x.x; r.y += x.y; r.z += x.z; r.w += x.w;
        }
    } else {
        r = comb2(p.pC0, p.pC1, p.MlC, SEQ, row - SEQ, c4);
    }
    float v[4] = {r.x, r.y, r.z, r.w};
    ushort hi[4], lo[4];
#pragma unroll
    for (int j = 0; j < 4; ++j) {
        hi[j] = f2bf(v[j]);
        lo[j] = f2bf(v[j] - bf2f(hi[j]));
    }
    const size_t o = (size_t)row * DIM + c4;
    *(uint2*)(p.Xh + o) = *(uint2*)hi;
    *(uint2*)(p.Xl + o) = *(uint2*)lo;
}

// ---------------------------------------------------------------------------
extern "C" void kernel_launch(void* const* d_in, const int* in_sizes, int n_in,
                              void* d_out, int out_size, void* d_ws, size_t ws_size,
                              hipStream_t stream) {
    (void)in_sizes; (void)n_in; (void)out_size; (void)ws_size;
    const void* hs   = d_in[0];
    const void* ehs  = d_in[1];
    const void* hsc  = d_in[2];
    const void* ehsc = d_in[3];
    const void* i2q  = d_in[4];
    const void* pe   = d_in[5];
#define W_(i) ((const void*)d_in[i])

    char* base = (char*)d_ws;
    int* flag = (int*)base;
    char* ptr = base + 256;
    auto alloc = [&](size_t bytes) { char* r = ptr; ptr += bytes; return r; };
    float* q1  = (float*)alloc(SD * 4);      // C q f32 (roped inplace); later Xl
    float* k1  = (float*)alloc(SD * 4);      // C k f32; later pA1
    float* v1  = (float*)alloc(SD * 4);      // A v f32; later pA0
    float* vC  = (float*)alloc(SD * 4);      // C v f32; later pC0
    float* qA  = (float*)alloc(SD * 4);      // A q f32; later Xh
    float* qx  = (float*)alloc(IDSZ * 4);    // X q f32
    ushort* khA  = (ushort*)alloc(SD * 2);
    ushort* kloA = (ushort*)alloc(SD * 2);
    ushort* vthA = (ushort*)alloc(SD * 2);
    ushort* vtlA = (ushort*)alloc(SD * 2);
    ushort* khC  = (ushort*)alloc(SD * 2);
    ushort* kloC = (ushort*)alloc(SD * 2);
    ushort* vthC = (ushort*)alloc(SD * 2);
    ushort* vtlC = (ushort*)alloc(SD * 2);
    float* pX0 = (float*)alloc(IDSZ * 4);
    float* pX1 = (float*)alloc(IDSZ * 4);
    float2* MlA = (float2*)alloc((size_t)2 * NH * SEQ * 8);
    float2* MlC = (float2*)alloc((size_t)2 * NH * SEQ * 8);
    float2* MlX = (float2*)alloc((size_t)2 * NH * IMG * 8);
    ushort* Wbf = (ushort*)alloc(16 * WSZ * 2);
    ushort* Xbf = (ushort*)alloc(2 * SD * 2);
    float* pC1 = (float*)Xbf;
    ushort* Xh = (ushort*)qA;
    ushort* Xl = (ushort*)q1;

    dim3 blk(256);
    detect_dtype<<<1, blk, 0, stream>>>(hs, flag);

    {
        CvtP cp;
        const int wsrc[16] = {6, 8, 10, 12, 14, 16, 22, 24, 26, 28, 30, 32,
                              18, 20, 34, 36};
        for (int j = 0; j < 16; ++j) {
            cp.src[j] = W_(wsrc[j]);
            cp.dst[j] = Wbf + (size_t)j * WSZ;
            cp.n8[j] = (int)(WSZ / 8);
        }
        cp.src[16] = hs;   cp.dst[16] = Xbf;             cp.n8[16] = (int)(IDSZ / 8);
        cp.src[17] = ehs;  cp.dst[17] = Xbf + IDSZ;      cp.n8[17] = (int)((size_t)TXT * DIM / 8);
        cp.src[18] = hsc;  cp.dst[18] = Xbf + SD;        cp.n8[18] = (int)(IDSZ / 8);
        cp.src[19] = ehsc; cp.dst[19] = Xbf + SD + IDSZ; cp.n8[19] = (int)((size_t)TXT * DIM / 8);
        convert_bf16<<<dim3((int)(WSZ / 8 + 255) / 256, 20), blk, 0, stream>>>(cp, flag);
    }

    QKV3P qp;
    qp.Xb = Xbf;
    qp.Wb = Wbf;
    {
        const int bsrc[12] = {7, 9, 11, 13, 15, 17, 23, 25, 27, 29, 31, 33};
        for (int j = 0; j < 12; ++j) qp.B[j] = W_(bsrc[j]);
    }
    for (int j = 0; j < 6; ++j) { qp.Y[j] = nullptr; qp.Yh[j] = nullptr; qp.Yl[j] = nullptr; }
    qp.Y[0] = qA;
    qp.Yh[1] = khA; qp.Yl[1] = kloA;
    qp.Y[2] = v1;
    qp.Y[3] = q1;
    qp.Y[4] = k1;
    qp.Y[5] = vC;
    gemm_qkv_v4<<<dim3(36, 20), blk, 0, stream>>>(qp, flag);

    {
        PrepP pp;
        pp.v1 = v1; pp.vC = vC;
        pp.vthA = vthA; pp.vtlA = vtlA; pp.vthC = vthC; pp.vtlC = vtlC;
        pp.q1 = q1;
        pp.k1 = k1; pp.khC = khC; pp.kloC = kloC;
        pp.i2q = i2q; pp.qx = qx;
        pp.pe = pe;
        const int ropeBlocks = (RN0 + RN1 + RN2 + 255) / 256;
        prep_fused<<<VT_BLKS + ropeBlocks, blk, 0, stream>>>(pp, flag);
    }

    {
        AttnAllP ap;
        ap.Qf[0] = qA; ap.Qf[1] = q1; ap.Qf[2] = qx;
        ap.Kh[0] = khA; ap.Kl[0] = kloA;
        ap.Kh[1] = khC; ap.Kl[1] = kloC;
        ap.Kh[2] = khC; ap.Kl[2] = kloC;
        ap.Vth[0] = vthA; ap.Vtl[0] = vtlA;
        ap.Vth[1] = vthC; ap.Vtl[1] = vtlC;
        ap.Vth[2] = vthC; ap.Vtl[2] = vtlC;
        ap.Op0[0] = v1;  ap.Op1[0] = k1;
        ap.Op0[1] = vC;  ap.Op1[1] = pC1;
        ap.Op0[2] = pX0; ap.Op1[2] = pX1;
        ap.Ml[0] = MlA; ap.Ml[1] = MlC; ap.Ml[2] = MlX;
        ap.mlq[0] = SEQ; ap.mlq[1] = SEQ; ap.mlq[2] = IMG;
        attn_all<<<dim3(56, NH, 2), blk, 0, stream>>>(ap);
    }

    {
        MergeP mp;
        mp.pA0 = v1; mp.pA1 = k1;
        mp.pC0 = vC; mp.pC1 = pC1;
        mp.pX0 = pX0; mp.pX1 = pX1;
        mp.MlA = MlA; mp.MlC = MlC; mp.MlX = MlX;
        mp.Xh = Xh; mp.Xl = Xl;
        merge_all<<<(2560 * 384 + 255) / 256, blk, 0, stream>>>(mp);
    }

    {
        OutP op;
        op.Xh = Xh; op.Xl = Xl;
        op.Wb = Wbf + (size_t)12 * WSZ;
        op.B[0] = W_(19); op.B[1] = W_(21); op.B[2] = W_(35); op.B[3] = W_(37);
        op.out = d_out;
        gemm_out_v4<<<dim3(12, 40), blk, 0, stream>>>(op, flag);
    }
#undef W_
}

// Round 6
// 552.193 us; speedup vs baseline: 1.2318x; 1.2318x over previous
//
#include <hip/hip_runtime.h>

#define DIM 1536
#define IMG 1024
#define TXT 256
#define SEQ 1280
#define NH 24
#define HD 64
#define SD ((size_t)SEQ * DIM)
#define IDSZ ((size_t)IMG * DIM)
#define WSZ ((size_t)DIM * DIM)

typedef __attribute__((ext_vector_type(8))) short short8;
typedef __attribute__((ext_vector_type(4))) float f32x4;

__device__ __forceinline__ float bf2f(ushort u) {
    union { unsigned int i; float f; } v; v.i = ((unsigned int)u) << 16; return v.f;
}
__device__ __forceinline__ ushort f2bf(float f) {
    union { unsigned int i; float f; } v; v.f = f;
    unsigned int u = v.i;
    u += 0x7fffu + ((u >> 16) & 1u);
    return (ushort)(u >> 16);
}
// Truncating f32 -> bf16 (round toward zero). Used ONLY for lo-residual
// planes where the value is already a 2^-8-scale residual.
__device__ __forceinline__ ushort f2bf_rz(float f) {
    union { unsigned int i; float f; } v; v.f = f;
    return (ushort)(v.i >> 16);
}

// ---------------------------------------------------------------------------
// Input-dtype detector (flag=1 -> fp32 underneath, flag=0 -> bf16).
// ---------------------------------------------------------------------------
__global__ __launch_bounds__(256) void detect_dtype(const void* __restrict__ p,
                                                    int* __restrict__ flag)
{
    __shared__ int cnt;
    if (threadIdx.x == 0) cnt = 0;
    __syncthreads();
    const ushort* u = (const ushort*)p;
    int local = 0;
    for (int i = threadIdx.x; i < 2048; i += 256) {
        ushort v = u[2 * i];
        int e = (v >> 7) & 0xFF;
        if (e >= 0xC0) local++;
    }
    atomicAdd(&cnt, local);
    __syncthreads();
    if (threadIdx.x == 0) flag[0] = (cnt > 16) ? 1 : 0;
}

// ---------------------------------------------------------------------------
// One-time bf16 conversion: 16 weights (12 qkv + 4 out) + 4 X inputs.
// ---------------------------------------------------------------------------
struct CvtP {
    const void* src[20];
    ushort* dst[20];
    int n8[20];
};

__global__ __launch_bounds__(256) void convert_bf16(CvtP p, const int* __restrict__ dflag)
{
    const int a = blockIdx.y;
    const int i = blockIdx.x * 256 + threadIdx.x;
    if (i >= p.n8[a]) return;
    const size_t off = (size_t)i * 8;
    uint4 o;
    if (dflag[0]) {
        const float* s = (const float*)p.src[a] + off;
        const float4 f0 = *(const float4*)s;
        const float4 f1 = *(const float4*)(s + 4);
        ushort t[8];
        t[0] = f2bf(f0.x); t[1] = f2bf(f0.y); t[2] = f2bf(f0.z); t[3] = f2bf(f0.w);
        t[4] = f2bf(f1.x); t[5] = f2bf(f1.y); t[6] = f2bf(f1.z); t[7] = f2bf(f1.w);
        o = *(uint4*)t;
    } else {
        o = *(const uint4*)((const ushort*)p.src[a] + off);
    }
    *(uint4*)(p.dst[a] + off) = o;
}

#define LSTR 40

// ===========================================================================
// Merged QKV GEMM over pre-converted bf16 X and W. grid (36, 20).
// B plane: 128 n-rows folded into 64 LDS rows of 64 ushorts, granule XOR
// gx = ((half<<2)+g) ^ (R&7) ^ (R>>3).
// ===========================================================================
struct QKV3P {
    const ushort* Xb;    // [2][SEQ][DIM] bf16
    const ushort* Wb;    // [12][DIM][DIM] bf16, idx = str*6 + wsel + istxt*3
    const void* B[12];
    float* Y[6];
    ushort* Yh[6];
    ushort* Yl[6];
};

__global__ __launch_bounds__(256) void gemm_qkv_v4(QKV3P p, const int* __restrict__ dflag)
{
    __shared__ __align__(16) ushort As[2][128 * LSTR];
    __shared__ __align__(16) ushort Bs[2][64 * 64];
    const int dt = dflag[0];
    const int bx = blockIdx.x;
    const int wsel = bx / 12;
    const int n0 = (bx - wsel * 12) * 128;
    const int ys = blockIdx.y;
    const int str = (ys >= 10) ? 1 : 0;
    const int m0g = (ys - str * 10) * 128;
    const bool istxt = (m0g >= IMG);
    const int widx = str * 6 + wsel + (istxt ? 3 : 0);
    const ushort* X  = p.Xb + (size_t)str * SD;
    const ushort* Wp = p.Wb + (size_t)widx * WSZ;
    const void* Bp = p.B[widx];
    const int yidx = str * 3 + wsel;
    float*  Y  = p.Y[yidx];
    ushort* yh = p.Yh[yidx];
    ushort* yl = p.Yl[yidx];

    const int t = threadIdx.x;
    const int wave = t >> 6, lane = t & 63;
    const int quad = lane >> 4, l16 = lane & 15;
    const int wm = (wave >> 1) * 64, wn = (wave & 1) * 64;

    const int arow = t >> 1, apair = t & 1;
    const int bn8 = (t & 15) << 3, bkk = (t >> 4) << 1;
    const int aps = apair ^ ((arow >> 3) & 1);
    const int adst = arow * LSTR + aps * 16;
    const int bkg = bkk >> 3, bo = bkk & 7;

    f32x4 acc[4][4];
#pragma unroll
    for (int i = 0; i < 4; ++i)
#pragma unroll
        for (int j = 0; j < 4; ++j) acc[i][j] = (f32x4)(0.0f);

    uint4 rau[2];
    uint4 rbu[2];

    auto loadA = [&](int k0) {
        const ushort* xp = X + (size_t)(m0g + arow) * DIM + k0 + apair * 16;
        rau[0] = *(const uint4*)xp;
        rau[1] = *(const uint4*)(xp + 8);
    };
    auto loadB = [&](int k0) {
        const ushort* wp0 = Wp + (size_t)(k0 + bkk) * DIM + n0 + bn8;
        rbu[0] = *(const uint4*)wp0;
        rbu[1] = *(const uint4*)(wp0 + DIM);
    };
    auto storeA = [&](int buf) {
        *(uint4*)&As[buf][adst]     = rau[0];
        *(uint4*)&As[buf][adst + 8] = rau[1];
    };
    auto storeB = [&](int buf) {
        ushort t0[8], t1[8];
        *(uint4*)t0 = rbu[0];
        *(uint4*)t1 = rbu[1];
#pragma unroll
        for (int j = 0; j < 8; ++j) {
            const int rr = bn8 + j;
            const int R = rr & 63, half = rr >> 6;
            const int gx = (((half << 2) + bkg) ^ (R & 7) ^ (R >> 3)) & 7;
            *(unsigned int*)&Bs[buf][R * 64 + gx * 8 + bo] =
                (unsigned int)t0[j] | ((unsigned int)t1[j] << 16);
        }
    };

    loadA(0); loadB(0);
    storeA(0); storeB(0);
    __syncthreads();

    for (int k = 0; k < DIM / 32; ++k) {
        const int cur = k & 1;
        const bool hn = (k + 1) < DIM / 32;
        if (hn) { loadA((k + 1) * 32); loadB((k + 1) * 32); }

        short8 b[4];
#pragma unroll
        for (int j = 0; j < 4; ++j) {
            const int rrn = wn + j * 16 + l16;
            const int R = rrn & 63, half = rrn >> 6;
            const int gx = (((half << 2) + quad) ^ (R & 7) ^ (R >> 3)) & 7;
            b[j] = *(const short8*)&Bs[cur][R * 64 + gx * 8];
        }
#pragma unroll
        for (int i = 0; i < 4; ++i) {
            const int rr = wm + i * 16 + l16;
            const int ps = (quad >> 1) ^ ((rr >> 3) & 1);
            const int col = ps * 16 + (quad & 1) * 8;
            short8 a = *(const short8*)&As[cur][rr * LSTR + col];
#pragma unroll
            for (int j = 0; j < 4; ++j)
                acc[i][j] = __builtin_amdgcn_mfma_f32_16x16x32_bf16(a, b[j], acc[i][j], 0, 0, 0);
        }
        if (hn) { storeA(cur ^ 1); storeB(cur ^ 1); }
        __syncthreads();
    }

#pragma unroll
    for (int j = 0; j < 4; ++j) {
        const int col = n0 + wn + j * 16 + l16;
        const float bv = dt ? ((const float*)Bp)[col] : bf2f(((const ushort*)Bp)[col]);
#pragma unroll
        for (int i = 0; i < 4; ++i)
#pragma unroll
            for (int r = 0; r < 4; ++r) {
                const int row = m0g + wm + i * 16 + quad * 4 + r;
                const size_t o = (size_t)row * DIM + col;
                const float val = acc[i][j][r] + bv;
                if (Y) Y[o] = val;
                if (yh) {
                    const ushort hv = f2bf(val);
                    yh[o] = hv;
                    yl[o] = f2bf(val - bf2f(hv));
                }
            }
    }
}

// ===========================================================================
// Output projections from pre-split bf16 A planes (Xh/Xl, 2560 rows) and
// pre-converted bf16 weights. grid (12, 40), 64-row m-tiles.
// ===========================================================================
struct OutP {
    const ushort* Xh; const ushort* Xl;
    const ushort* Wb;    // 4 * WSZ bf16
    const void* B[4];
    void* out;
};

__global__ __launch_bounds__(256) void gemm_out_v4(OutP p, const int* __restrict__ dflag)
{
    __shared__ __align__(16) ushort Ah[2][64 * LSTR];
    __shared__ __align__(16) ushort Al[2][64 * LSTR];
    __shared__ __align__(16) ushort Bs[2][64 * 64];
    const int dt = dflag[0];
    const int n0 = blockIdx.x * 128;
    const int mt = blockIdx.y;
    const int seg = (mt < 16) ? 0 : (mt < 20) ? 1 : (mt < 36) ? 2 : 3;
    const ushort* Wp = p.Wb + (size_t)seg * WSZ;
    const void* Bp = p.B[seg];
    const int m0 = mt * 64;

    const int t = threadIdx.x;
    const int wave = t >> 6, lane = t & 63;
    const int quad = lane >> 4, l16 = lane & 15;
    const int wm = (wave >> 1) * 32, wn = (wave & 1) * 64;

    const int arow = t >> 2, ag = t & 3;
    const int apg = ag >> 1, asub = ag & 1;
    const int aps = apg ^ ((arow >> 3) & 1);
    const int adst = arow * LSTR + aps * 16 + asub * 8;
    const int bn8 = (t & 15) << 3, bkk = (t >> 4) << 1;
    const int bkg = bkk >> 3, bo = bkk & 7;

    f32x4 acc[2][4];
#pragma unroll
    for (int i = 0; i < 2; ++i)
#pragma unroll
        for (int j = 0; j < 4; ++j) acc[i][j] = (f32x4)(0.0f);

    uint4 rah, ral;
    uint4 rbu[2];

    auto loadA = [&](int k0) {
        const size_t off = (size_t)(m0 + arow) * DIM + k0 + ag * 8;
        rah = *(const uint4*)(p.Xh + off);
        ral = *(const uint4*)(p.Xl + off);
    };
    auto loadB = [&](int k0) {
        const ushort* wp0 = Wp + (size_t)(k0 + bkk) * DIM + n0 + bn8;
        rbu[0] = *(const uint4*)wp0;
        rbu[1] = *(const uint4*)(wp0 + DIM);
    };
    auto storeA = [&](int buf) {
        *(uint4*)&Ah[buf][adst] = rah;
        *(uint4*)&Al[buf][adst] = ral;
    };
    auto storeB = [&](int buf) {
        ushort t0[8], t1[8];
        *(uint4*)t0 = rbu[0];
        *(uint4*)t1 = rbu[1];
#pragma unroll
        for (int j = 0; j < 8; ++j) {
            const int rr = bn8 + j;
            const int R = rr & 63, half = rr >> 6;
            const int gx = (((half << 2) + bkg) ^ (R & 7) ^ (R >> 3)) & 7;
            *(unsigned int*)&Bs[buf][R * 64 + gx * 8 + bo] =
                (unsigned int)t0[j] | ((unsigned int)t1[j] << 16);
        }
    };

    loadA(0); loadB(0);
    storeA(0); storeB(0);
    __syncthreads();

    for (int k = 0; k < DIM / 32; ++k) {
        const int cur = k & 1;
        const bool hn = (k + 1) < DIM / 32;
        if (hn) { loadA((k + 1) * 32); loadB((k + 1) * 32); }

        short8 b[4];
#pragma unroll
        for (int j = 0; j < 4; ++j) {
            const int rrn = wn + j * 16 + l16;
            const int R = rrn & 63, half = rrn >> 6;
            const int gx = (((half << 2) + quad) ^ (R & 7) ^ (R >> 3)) & 7;
            b[j] = *(const short8*)&Bs[cur][R * 64 + gx * 8];
        }
#pragma unroll
        for (int i = 0; i < 2; ++i) {
            const int rr = wm + i * 16 + l16;
            const int ps = (quad >> 1) ^ ((rr >> 3) & 1);
            const int col = ps * 16 + (quad & 1) * 8;
            short8 ah = *(const short8*)&Ah[cur][rr * LSTR + col];
            short8 al = *(const short8*)&Al[cur][rr * LSTR + col];
#pragma unroll
            for (int j = 0; j < 4; ++j) {
                acc[i][j] = __builtin_amdgcn_mfma_f32_16x16x32_bf16(ah, b[j], acc[i][j], 0, 0, 0);
                acc[i][j] = __builtin_amdgcn_mfma_f32_16x16x32_bf16(al, b[j], acc[i][j], 0, 0, 0);
            }
        }
        if (hn) { storeA(cur ^ 1); storeB(cur ^ 1); }
        __syncthreads();
    }

#pragma unroll
    for (int j = 0; j < 4; ++j) {
        const int col = n0 + wn + j * 16 + l16;
        const float bv = dt ? ((const float*)Bp)[col] : bf2f(((const ushort*)Bp)[col]);
#pragma unroll
        for (int i = 0; i < 2; ++i)
#pragma unroll
            for (int r = 0; r < 4; ++r) {
                const int grow = m0 + wm + i * 16 + quad * 4 + r;
                const size_t o = (size_t)grow * DIM + col;
                const float val = acc[i][j][r] + bv;
                if (dt) ((float*)p.out)[o] = val;
                else    ((ushort*)p.out)[o] = f2bf(val);
            }
    }
}

// ---------------------------------------------------------------------------
// Fused prep: vtrans (both streams) + all three RoPE jobs in one launch.
// ---------------------------------------------------------------------------
__device__ __forceinline__ void pe_load(const void* pe, int dt, size_t off,
                                        float& c00, float& c01, float& c10, float& c11)
{
    if (dt) {
        float4 pv = *(const float4*)((const float*)pe + off);
        c00 = pv.x; c01 = pv.y; c10 = pv.z; c11 = pv.w;
    } else {
        const ushort* pp = (const ushort*)pe + off;
        c00 = bf2f(pp[0]); c01 = bf2f(pp[1]); c10 = bf2f(pp[2]); c11 = bf2f(pp[3]);
    }
}

struct PrepP {
    const float* v1; const float* vC;
    ushort *vthA, *vtlA, *vthC, *vtlC;
    float* q1;
    const float* k1; ushort *khC, *kloC;
    const void* i2q; float* qx;
    const void* pe;
};

#define VT_BLKS 960
#define RN0 (SEQ * 768)
#define RN1 (SEQ * 768)
#define RN2 (IMG * 768)

__global__ __launch_bounds__(256) void prep_fused(PrepP p, const int* __restrict__ dflag)
{
    __shared__ unsigned int tile[64 * 65];
    const int dt = dflag[0];
    const int bx = blockIdx.x;
    const int t = threadIdx.x;

    if (bx < VT_BLKS) {
        const int z = bx / 480, rem = bx - z * 480;
        const int s0 = (rem % 20) * 64, h = rem / 20;
        const float* V = z ? p.vC : p.v1;
        ushort* Vth = z ? p.vthC : p.vthA;
        ushort* Vtl = z ? p.vtlC : p.vtlA;
#pragma unroll
        for (int it = 0; it < 16; ++it) {
            const int sl = (t >> 6) + (it << 2);
            const int d = t & 63;
            const float v = V[(size_t)(s0 + sl) * DIM + h * HD + d];
            const ushort hv = f2bf(v);
            const ushort lv = f2bf(v - bf2f(hv));
            tile[d * 65 + sl] = (unsigned int)hv | ((unsigned int)lv << 16);
        }
        __syncthreads();
        const int d = t >> 2, cc = (t & 3) << 4;
        ushort th[16], tl[16];
#pragma unroll
        for (int j = 0; j < 16; ++j) {
            const unsigned int w = tile[d * 65 + cc + j];
            th[j] = (ushort)w;
            tl[j] = (ushort)(w >> 16);
        }
        const size_t off = (size_t)(h * HD + d) * SEQ + s0 + cc;
        *(uint4*)(Vth + off)     = *(uint4*)&th[0];
        *(uint4*)(Vth + off + 8) = *(uint4*)&th[8];
        *(uint4*)(Vtl + off)     = *(uint4*)&tl[0];
        *(uint4*)(Vtl + off + 8) = *(uint4*)&tl[8];
        return;
    }

    int idx = (bx - VT_BLKS) * 256 + t;
    if (idx < RN0) {
        int s = idx / 768, pp = idx - s * 768;
        int col = pp << 1, i = pp & 31;
        float* bp = p.q1 + (size_t)s * DIM + col;
        float x0 = bp[0], x1 = bp[1];
        float c00, c01, c10, c11;
        pe_load(p.pe, dt, (size_t)s * 128 + i * 4, c00, c01, c10, c11);
        bp[0] = c00 * x0 + c01 * x1;
        bp[1] = c10 * x0 + c11 * x1;
        return;
    }
    idx -= RN0;
    if (idx < RN1) {
        int s = idx / 768, pp = idx - s * 768;
        int col = pp << 1, i = pp & 31;
        float2 xv = *(const float2*)(p.k1 + (size_t)s * DIM + col);
        float c00, c01, c10, c11;
        pe_load(p.pe, dt, (size_t)s * 128 + i * 4, c00, c01, c10, c11);
        float y0 = c00 * xv.x + c01 * xv.y;
        float y1 = c10 * xv.x + c11 * xv.y;
        ushort h0 = f2bf(y0), h1 = f2bf(y1);
        ushort l0 = f2bf(y0 - bf2f(h0)), l1 = f2bf(y1 - bf2f(h1));
        *(unsigned int*)(p.khC  + (size_t)s * DIM + col) = (unsigned int)h0 | ((unsigned int)h1 << 16);
        *(unsigned int*)(p.kloC + (size_t)s * DIM + col) = (unsigned int)l0 | ((unsigned int)l1 << 16);
        return;
    }
    idx -= RN1;
    if (idx < RN2) {
        int s = idx / 768, pp = idx - s * 768;
        int col = pp << 1, i = pp & 31;
        float x0, x1;
        if (dt) {
            float2 xv = *(const float2*)((const float*)p.i2q + (size_t)s * DIM + col);
            x0 = xv.x; x1 = xv.y;
        } else {
            const ushort* sp = (const ushort*)p.i2q + (size_t)s * DIM + col;
            x0 = bf2f(sp[0]); x1 = bf2f(sp[1]);
        }
        float c00, c01, c10, c11;
        pe_load(p.pe, dt, (size_t)s * 128 + i * 4, c00, c01, c10, c11);
        float* dp = p.qx + (size_t)s * DIM + col;
        dp[0] = c00 * x0 + c01 * x1;
        dp[1] = c10 * x0 + c11 * x1;
    }
}

// ---------------------------------------------------------------------------
// MFMA flash attention, all three attentions in one launch. grid (56, NH, 2).
// v6 = round-4 structure (no register prefetch, no launch_bounds min-waves,
// no offset arrays — all were scratch-spill hazards, measured v5) plus:
//   - 0.125 softmax scale folded into Q staging (pow2, bit-exact)
//   - truncating conversion for the P lo-residual plane
// ---------------------------------------------------------------------------
__device__ __forceinline__ int swz(int row, int col) {
    return row * 64 + ((((col >> 3) ^ row) & 7) << 3) + (col & 7);
}
__device__ __forceinline__ short8 ldfrag(const ushort* plane, int row, int col) {
    return *(const short8*)&plane[swz(row, col)];
}

struct AttnAllP {
    const float* Qf[3];
    const ushort* Kh[3]; const ushort* Kl[3];
    const ushort* Vth[3]; const ushort* Vtl[3];
    float* Op0[3]; float* Op1[3];
    float2* Ml[3];
    int mlq[3];
};

__global__ __launch_bounds__(256) void attn_all(AttnAllP p)
{
    __shared__ ushort Qh_[4096], Ql_[4096];
    __shared__ ushort Kh_[4096], Kl_[4096];
    __shared__ ushort Vh_[4096], Vl_[4096];

    const int bx = blockIdx.x;
    const int seg = (bx < 20) ? 0 : (bx < 40) ? 1 : 2;
    const int q0 = (bx - ((seg == 0) ? 0 : (seg == 1) ? 20 : 40)) * 64;
    const int h = blockIdx.y;
    const int z = blockIdx.z;
    const int t = threadIdx.x;
    const int wave = t >> 6, lane = t & 63;
    const int quad = lane >> 4, l16 = lane & 15;
    const int wq0 = wave * 16;

    const float* Qf = p.Qf[seg];
    const ushort* Kh = p.Kh[seg]; const ushort* Kl = p.Kl[seg];
    const ushort* Vth = p.Vth[seg]; const ushort* Vtl = p.Vtl[seg];

    const int srow = t >> 2, c0 = (t & 3) << 4;
    const int g0 = c0 >> 3;
    const int p0 = ((g0 ^ (srow & 7)) & 7) << 3;
    const int p1 = (((g0 + 1) ^ (srow & 7)) & 7) << 3;

    // ---- Q staging, 0.125 softmax scale folded in (exact pow2) ----
    {
        const float* src = Qf + (size_t)(q0 + srow) * DIM + h * HD + c0;
        float x[16];
        *(float4*)&x[0]  = *(const float4*)(src);
        *(float4*)&x[4]  = *(const float4*)(src + 4);
        *(float4*)&x[8]  = *(const float4*)(src + 8);
        *(float4*)&x[12] = *(const float4*)(src + 12);
        ushort hi[16], lo[16];
#pragma unroll
        for (int i = 0; i < 16; ++i) {
            const float xs = x[i] * 0.125f;
            hi[i] = f2bf(xs);
            lo[i] = f2bf(xs - bf2f(hi[i]));
        }
        *(uint4*)&Qh_[srow * 64 + p0] = *(uint4*)&hi[0];
        *(uint4*)&Qh_[srow * 64 + p1] = *(uint4*)&hi[8];
        *(uint4*)&Ql_[srow * 64 + p0] = *(uint4*)&lo[0];
        *(uint4*)&Ql_[srow * 64 + p1] = *(uint4*)&lo[8];
    }
    // Within-wave store->read (wave stages its own 16 rows; no barrier).
    short8 qfh[2], qfl[2];
#pragma unroll
    for (int c = 0; c < 2; ++c) {
        qfh[c] = ldfrag(Qh_, wq0 + l16, c * 32 + quad * 8);
        qfl[c] = ldfrag(Ql_, wq0 + l16, c * 32 + quad * 8);
    }

    float m_[4], l_[4];
#pragma unroll
    for (int r = 0; r < 4; ++r) { m_[r] = -3e38f; l_[r] = 0.0f; }
    f32x4 Oacc[4];
#pragma unroll
    for (int j = 0; j < 4; ++j) Oacc[j] = (f32x4)(0.0f);

    const int kvbeg = z * (SEQ / 2);
    for (int kt = 0; kt < SEQ / 2; kt += 64) {
        const int kv0 = kvbeg + kt;
        __syncthreads();
        {
            const size_t off = (size_t)(kv0 + srow) * DIM + h * HD + c0;
            *(uint4*)&Kh_[srow * 64 + p0] = *(const uint4*)(Kh + off);
            *(uint4*)&Kh_[srow * 64 + p1] = *(const uint4*)(Kh + off + 8);
            *(uint4*)&Kl_[srow * 64 + p0] = *(const uint4*)(Kl + off);
            *(uint4*)&Kl_[srow * 64 + p1] = *(const uint4*)(Kl + off + 8);
        }
        {
            const size_t off = (size_t)(h * HD + srow) * SEQ + kv0 + c0;
            *(uint4*)&Vh_[srow * 64 + p0] = *(const uint4*)(Vth + off);
            *(uint4*)&Vh_[srow * 64 + p1] = *(const uint4*)(Vth + off + 8);
            *(uint4*)&Vl_[srow * 64 + p0] = *(const uint4*)(Vtl + off);
            *(uint4*)&Vl_[srow * 64 + p1] = *(const uint4*)(Vtl + off + 8);
        }
        __syncthreads();

        f32x4 S[4];
#pragma unroll
        for (int j = 0; j < 4; ++j) S[j] = (f32x4)(0.0f);
        __builtin_amdgcn_s_setprio(1);
#pragma unroll
        for (int c = 0; c < 2; ++c) {
#pragma unroll
            for (int j = 0; j < 4; ++j) {
                short8 bh = ldfrag(Kh_, j * 16 + l16, c * 32 + quad * 8);
                short8 bl = ldfrag(Kl_, j * 16 + l16, c * 32 + quad * 8);
                S[j] = __builtin_amdgcn_mfma_f32_16x16x32_bf16(qfh[c], bh, S[j], 0, 0, 0);
                S[j] = __builtin_amdgcn_mfma_f32_16x16x32_bf16(qfl[c], bh, S[j], 0, 0, 0);
                S[j] = __builtin_amdgcn_mfma_f32_16x16x32_bf16(qfh[c], bl, S[j], 0, 0, 0);
            }
        }
        __builtin_amdgcn_s_setprio(0);

        float alpha[4];
#pragma unroll
        for (int r = 0; r < 4; ++r) {
            float mx = fmaxf(fmaxf(S[0][r], S[1][r]), fmaxf(S[2][r], S[3][r]));
            mx = fmaxf(mx, __shfl_xor(mx, 1));
            mx = fmaxf(mx, __shfl_xor(mx, 2));
            mx = fmaxf(mx, __shfl_xor(mx, 4));
            mx = fmaxf(mx, __shfl_xor(mx, 8));
            float mn = fmaxf(m_[r], mx);
            alpha[r] = __expf(m_[r] - mn);
            m_[r] = mn;
            float rs = 0.0f;
#pragma unroll
            for (int j = 0; j < 4; ++j) {
                float pv = __expf(S[j][r] - mn);
                S[j][r] = pv;
                rs += pv;
            }
            rs += __shfl_xor(rs, 1);
            rs += __shfl_xor(rs, 2);
            rs += __shfl_xor(rs, 4);
            rs += __shfl_xor(rs, 8);
            l_[r] = l_[r] * alpha[r] + rs;
        }
#pragma unroll
        for (int j = 0; j < 4; ++j)
#pragma unroll
            for (int r = 0; r < 4; ++r) Oacc[j][r] *= alpha[r];

        {
            const int prow = wq0 + quad * 4;
#pragma unroll
            for (int j = 0; j < 4; ++j)
#pragma unroll
                for (int r = 0; r < 4; ++r) {
                    float pv = S[j][r];
                    ushort ph = f2bf(pv);
                    ushort pl = f2bf_rz(pv - bf2f(ph));   // residual: truncation is enough
                    int idx = swz(prow + r, j * 16 + l16);
                    Qh_[idx] = ph;
                    Ql_[idx] = pl;
                }
        }

        __builtin_amdgcn_s_setprio(1);
#pragma unroll
        for (int c = 0; c < 2; ++c) {
            short8 pah = ldfrag(Qh_, wq0 + l16, c * 32 + quad * 8);
            short8 pal = ldfrag(Ql_, wq0 + l16, c * 32 + quad * 8);
#pragma unroll
            for (int jn = 0; jn < 4; ++jn) {
                short8 vbh = ldfrag(Vh_, jn * 16 + l16, c * 32 + quad * 8);
                short8 vbl = ldfrag(Vl_, jn * 16 + l16, c * 32 + quad * 8);
                Oacc[jn] = __builtin_amdgcn_mfma_f32_16x16x32_bf16(pah, vbh, Oacc[jn], 0, 0, 0);
                Oacc[jn] = __builtin_amdgcn_mfma_f32_16x16x32_bf16(pal, vbh, Oacc[jn], 0, 0, 0);
                Oacc[jn] = __builtin_amdgcn_mfma_f32_16x16x32_bf16(pah, vbl, Oacc[jn], 0, 0, 0);
            }
        }
        __builtin_amdgcn_s_setprio(0);
    }

    float* Opz = z ? p.Op1[seg] : p.Op0[seg];
    const int mlq = p.mlq[seg];
    float2* Ml = p.Ml[seg];
#pragma unroll
    for (int r = 0; r < 4; ++r) {
        const int rowq = q0 + wq0 + quad * 4 + r;
        if (l16 == 0)
            Ml[((size_t)z * NH + h) * mlq + rowq] = make_float2(m_[r], l_[r]);
#pragma unroll
        for (int jn = 0; jn < 4; ++jn)
            Opz[(size_t)rowq * DIM + h * HD + jn * 16 + l16] = Oacc[jn][r];
    }
}

// ---------------------------------------------------------------------------
// Unified merge: combines z-partials for A/C/X, folds cross residual into A,
// emits the out-proj A operand as bf16 hi/lo planes (2560 rows).
// ---------------------------------------------------------------------------
struct MergeP {
    const float *pA0, *pA1, *pC0, *pC1, *pX0, *pX1;
    const float2 *MlA, *MlC, *MlX;
    ushort *Xh, *Xl;
};

__device__ __forceinline__ float4 comb2(const float* O0, const float* O1,
                                        const float2* Ml, int mlq, int row, int c4)
{
    const int h = c4 >> 6;
    const float2 a = Ml[(size_t)h * mlq + row];
    const float2 b = Ml[(size_t)(NH + h) * mlq + row];
    const float ms = fmaxf(a.x, b.x);
    const float s0 = __expf(a.x - ms), s1 = __expf(b.x - ms);
    const float inv = 1.0f / (s0 * a.y + s1 * b.y);
    const float4 o0 = *(const float4*)&O0[(size_t)row * DIM + c4];
    const float4 o1 = *(const float4*)&O1[(size_t)row * DIM + c4];
    float4 r;
    r.x = (s0 * o0.x + s1 * o1.x) * inv;
    r.y = (s0 * o0.y + s1 * o1.y) * inv;
    r.z = (s0 * o0.z + s1 * o1.z) * inv;
    r.w = (s0 * o0.w + s1 * o1.w) * inv;
    return r;
}

__global__ __launch_bounds__(256) void merge_all(MergeP p)
{
    const int idx = blockIdx.x * 256 + threadIdx.x;
    if (idx >= 2560 * 384) return;
    const int row = idx / 384;
    const int c4 = (idx - row * 384) << 2;
    float4 r;
    if (row < SEQ) {
        r = comb2(p.pA0, p.pA1, p.MlA, SEQ, row, c4);
        if (row < IMG) {
            const float4 x = comb2(p.pX0, p.pX1, p.MlX, IMG, row, c4);
            r.x += x.x; r.y += x.y; r.z += x.z; r.w += x.w;
        }
    } else {
        r = comb2(p.pC0, p.pC1, p.MlC, SEQ, row - SEQ, c4);
    }
    float v[4] = {r.x, r.y, r.z, r.w};
    ushort hi[4], lo[4];
#pragma unroll
    for (int j = 0; j < 4; ++j) {
        hi[j] = f2bf(v[j]);
        lo[j] = f2bf(v[j] - bf2f(hi[j]));
    }
    const size_t o = (size_t)row * DIM + c4;
    *(uint2*)(p.Xh + o) = *(uint2*)hi;
    *(uint2*)(p.Xl + o) = *(uint2*)lo;
}

// ---------------------------------------------------------------------------
extern "C" void kernel_launch(void* const* d_in, const int* in_sizes, int n_in,
                              void* d_out, int out_size, void* d_ws, size_t ws_size,
                              hipStream_t stream) {
    (void)in_sizes; (void)n_in; (void)out_size; (void)ws_size;
    const void* hs   = d_in[0];
    const void* ehs  = d_in[1];
    const void* hsc  = d_in[2];
    const void* ehsc = d_in[3];
    const void* i2q  = d_in[4];
    const void* pe   = d_in[5];
#define W_(i) ((const void*)d_in[i])

    char* base = (char*)d_ws;
    int* flag = (int*)base;
    char* ptr = base + 256;
    auto alloc = [&](size_t bytes) { char* r = ptr; ptr += bytes; return r; };
    float* q1  = (float*)alloc(SD * 4);      // C q f32 (roped inplace); later Xl
    float* k1  = (float*)alloc(SD * 4);      // C k f32; later pA1
    float* v1  = (float*)alloc(SD * 4);      // A v f32; later pA0
    float* vC  = (float*)alloc(SD * 4);      // C v f32; later pC0
    float* qA  = (float*)alloc(SD * 4);      // A q f32; later Xh
    float* qx  = (float*)alloc(IDSZ * 4);    // X q f32
    ushort* khA  = (ushort*)alloc(SD * 2);
    ushort* kloA = (ushort*)alloc(SD * 2);
    ushort* vthA = (ushort*)alloc(SD * 2);
    ushort* vtlA = (ushort*)alloc(SD * 2);
    ushort* khC  = (ushort*)alloc(SD * 2);
    ushort* kloC = (ushort*)alloc(SD * 2);
    ushort* vthC = (ushort*)alloc(SD * 2);
    ushort* vtlC = (ushort*)alloc(SD * 2);
    float* pX0 = (float*)alloc(IDSZ * 4);
    float* pX1 = (float*)alloc(IDSZ * 4);
    float2* MlA = (float2*)alloc((size_t)2 * NH * SEQ * 8);
    float2* MlC = (float2*)alloc((size_t)2 * NH * SEQ * 8);
    float2* MlX = (float2*)alloc((size_t)2 * NH * IMG * 8);
    ushort* Wbf = (ushort*)alloc(16 * WSZ * 2);
    ushort* Xbf = (ushort*)alloc(2 * SD * 2);
    float* pC1 = (float*)Xbf;
    ushort* Xh = (ushort*)qA;
    ushort* Xl = (ushort*)q1;

    dim3 blk(256);
    detect_dtype<<<1, blk, 0, stream>>>(hs, flag);

    {
        CvtP cp;
        const int wsrc[16] = {6, 8, 10, 12, 14, 16, 22, 24, 26, 28, 30, 32,
                              18, 20, 34, 36};
        for (int j = 0; j < 16; ++j) {
            cp.src[j] = W_(wsrc[j]);
            cp.dst[j] = Wbf + (size_t)j * WSZ;
            cp.n8[j] = (int)(WSZ / 8);
        }
        cp.src[16] = hs;   cp.dst[16] = Xbf;             cp.n8[16] = (int)(IDSZ / 8);
        cp.src[17] = ehs;  cp.dst[17] = Xbf + IDSZ;      cp.n8[17] = (int)((size_t)TXT * DIM / 8);
        cp.src[18] = hsc;  cp.dst[18] = Xbf + SD;        cp.n8[18] = (int)(IDSZ / 8);
        cp.src[19] = ehsc; cp.dst[19] = Xbf + SD + IDSZ; cp.n8[19] = (int)((size_t)TXT * DIM / 8);
        convert_bf16<<<dim3((int)(WSZ / 8 + 255) / 256, 20), blk, 0, stream>>>(cp, flag);
    }

    QKV3P qp;
    qp.Xb = Xbf;
    qp.Wb = Wbf;
    {
        const int bsrc[12] = {7, 9, 11, 13, 15, 17, 23, 25, 27, 29, 31, 33};
        for (int j = 0; j < 12; ++j) qp.B[j] = W_(bsrc[j]);
    }
    for (int j = 0; j < 6; ++j) { qp.Y[j] = nullptr; qp.Yh[j] = nullptr; qp.Yl[j] = nullptr; }
    qp.Y[0] = qA;
    qp.Yh[1] = khA; qp.Yl[1] = kloA;
    qp.Y[2] = v1;
    qp.Y[3] = q1;
    qp.Y[4] = k1;
    qp.Y[5] = vC;
    gemm_qkv_v4<<<dim3(36, 20), blk, 0, stream>>>(qp, flag);

    {
        PrepP pp;
        pp.v1 = v1; pp.vC = vC;
        pp.vthA = vthA; pp.vtlA = vtlA; pp.vthC = vthC; pp.vtlC = vtlC;
        pp.q1 = q1;
        pp.k1 = k1; pp.khC = khC; pp.kloC = kloC;
        pp.i2q = i2q; pp.qx = qx;
        pp.pe = pe;
        const int ropeBlocks = (RN0 + RN1 + RN2 + 255) / 256;
        prep_fused<<<VT_BLKS + ropeBlocks, blk, 0, stream>>>(pp, flag);
    }

    {
        AttnAllP ap;
        ap.Qf[0] = qA; ap.Qf[1] = q1; ap.Qf[2] = qx;
        ap.Kh[0] = khA; ap.Kl[0] = kloA;
        ap.Kh[1] = khC; ap.Kl[1] = kloC;
        ap.Kh[2] = khC; ap.Kl[2] = kloC;
        ap.Vth[0] = vthA; ap.Vtl[0] = vtlA;
        ap.Vth[1] = vthC; ap.Vtl[1] = vtlC;
        ap.Vth[2] = vthC; ap.Vtl[2] = vtlC;
        ap.Op0[0] = v1;  ap.Op1[0] = k1;
        ap.Op0[1] = vC;  ap.Op1[1] = pC1;
        ap.Op0[2] = pX0; ap.Op1[2] = pX1;
        ap.Ml[0] = MlA; ap.Ml[1] = MlC; ap.Ml[2] = MlX;
        ap.mlq[0] = SEQ; ap.mlq[1] = SEQ; ap.mlq[2] = IMG;
        attn_all<<<dim3(56, NH, 2), blk, 0, stream>>>(ap);
    }

    {
        MergeP mp;
        mp.pA0 = v1; mp.pA1 = k1;
        mp.pC0 = vC; mp.pC1 = pC1;
        mp.pX0 = pX0; mp.pX1 = pX1;
        mp.MlA = MlA; mp.MlC = MlC; mp.MlX = MlX;
        mp.Xh = Xh; mp.Xl = Xl;
        merge_all<<<(2560 * 384 + 255) / 256, blk, 0, stream>>>(mp);
    }

    {
        OutP op;
        op.Xh = Xh; op.Xl = Xl;
        op.Wb = Wbf + (size_t)12 * WSZ;
        op.B[0] = W_(19); op.B[1] = W_(21); op.B[2] = W_(35); op.B[3] = W_(37);
        op.out = d_out;
        gemm_out_v4<<<dim3(12, 40), blk, 0, stream>>>(op, flag);
    }
#undef W_
}